// Round 1
// 24624.603 us; speedup vs baseline: 1.4315x; 1.4315x over previous
//
#include <hip/hip_runtime.h>
#include <math.h>

#define B 4
#define SEQ 33
#define MAXLEN 32
#define D 640
#define NH 8
#define DH 80
#define NL 6
#define FF 2560
#define V 30000
#define INITLEN 8
#define NBLK 1024
#define NT 256
#define EOS_TOK 2
#define NPOS_P 9
#define NR_P 36
#define LM_NB 938   // ceil(30000/32)

// striped stage flags: 32 slots x 64B per flag, relaxed RMW + wave-summed polls
#define NFLAGS 1024
#define NSLOT 32
#define SLOT_U 16   // uints per slot (64 bytes)

struct Par {
  const int* iw;
  const float* emb;
  const float *Wq, *bq, *Wk, *bk, *Wv, *bv, *Wo, *bo;
  const float *ln1s, *ln1b, *W1, *b1, *W2, *b2, *ln2s, *ln2b, *lmW, *lmb;
  int* out;
};

// ---------------- persistent device scratch ----------------------------------
__device__ float g_Kc[(size_t)NL * B * NH * SEQ * DH];
__device__ float g_Vc[(size_t)NL * B * NH * SEQ * DH];
// decode buffers
__device__ float g_x[B * D];
__device__ float g_h1[B * D];
__device__ float g_qkvp[(size_t)16 * 1920 * B];
__device__ float g_opart[(size_t)NH * D * B];
__device__ float g_f1p[(size_t)16 * FF * B];
__device__ float g_f2p[(size_t)32 * D * B];
// prefill buffers (36 rows)
__device__ float g_xp[NR_P * D];
__device__ float g_h1p[NR_P * D];
__device__ float g_qkvpP[(size_t)8 * 1920 * NR_P];
__device__ float g_qP[(size_t)NH * NR_P * DH];
__device__ float g_opartP[(size_t)NH * D * NR_P];
__device__ float g_f1pP[(size_t)8 * FF * NR_P];
__device__ float g_f2pP[(size_t)32 * D * NR_P];
// control
__device__ unsigned long long g_keys[(size_t)NBLK * B];
__device__ int g_tokens[B * SEQ];
__device__ int g_tok[B];
__device__ int g_stop;
__device__ unsigned g_flags[(size_t)NFLAGS * NSLOT * SLOT_U];
__device__ unsigned g_arrive = 0;
__device__ unsigned g_gen = 0;

#define KCIDX(l,b,h,pos,j) (((((size_t)(l)*B+(b))*NH+(h))*SEQ+(pos))*DH+(j))

// ---------------- fine-grained coherent access (sc1, bypass L2) --------------
__device__ __forceinline__ float ldc(const float* p) {
  return __hip_atomic_load(p, __ATOMIC_RELAXED, __HIP_MEMORY_SCOPE_AGENT);
}
__device__ __forceinline__ void stc(float* p, float v) {
  __hip_atomic_store(p, v, __ATOMIC_RELAXED, __HIP_MEMORY_SCOPE_AGENT);
}
__device__ __forceinline__ int ldci(const int* p) {
  return __hip_atomic_load(p, __ATOMIC_RELAXED, __HIP_MEMORY_SCOPE_AGENT);
}
__device__ __forceinline__ void stci(int* p, int v) {
  __hip_atomic_store(p, v, __ATOMIC_RELAXED, __HIP_MEMORY_SCOPE_AGENT);
}
__device__ __forceinline__ unsigned long long ldcu64(const unsigned long long* p) {
  return __hip_atomic_load(p, __ATOMIC_RELAXED, __HIP_MEMORY_SCOPE_AGENT);
}
__device__ __forceinline__ void stcu64(unsigned long long* p, unsigned long long v) {
  __hip_atomic_store(p, v, __ATOMIC_RELAXED, __HIP_MEMORY_SCOPE_AGENT);
}

// ---------------- init-time full grid barrier (cold path, keeps fences) ------
__device__ __forceinline__ void gsync_full() {
  __syncthreads();
  if (threadIdx.x == 0) {
    __threadfence();
    unsigned g = __hip_atomic_load(&g_gen, __ATOMIC_SEQ_CST, __HIP_MEMORY_SCOPE_AGENT);
    unsigned old = __hip_atomic_fetch_add(&g_arrive, 1u, __ATOMIC_SEQ_CST, __HIP_MEMORY_SCOPE_AGENT);
    if (old == NBLK - 1u) {
      __hip_atomic_store(&g_arrive, 0u, __ATOMIC_SEQ_CST, __HIP_MEMORY_SCOPE_AGENT);
      __hip_atomic_fetch_add(&g_gen, 1u, __ATOMIC_SEQ_CST, __HIP_MEMORY_SCOPE_AGENT);
    } else {
      while (__hip_atomic_load(&g_gen, __ATOMIC_RELAXED, __HIP_MEMORY_SCOPE_AGENT) == g)
        __builtin_amdgcn_s_sleep(2);
    }
    __threadfence();
  }
  __syncthreads();
}

// ---------------- fence-free striped stage sync ------------------------------
// Correctness: all cross-block data uses sc1 (agent-relaxed) accesses that hit
// the device coherence point directly, so no L2 writeback/invalidate is needed.
// __syncthreads() drains each wave's vmcnt (hipcc emits s_waitcnt vmcnt(0)
// before s_barrier), so producers' sc1 stores are globally visible before the
// flag increment issued after the barrier.
__device__ __forceinline__ void stage_done(int idx) {
  __syncthreads();
  if (threadIdx.x == 0) {
    asm volatile("s_waitcnt vmcnt(0)" ::: "memory");
    __hip_atomic_fetch_add(
        &g_flags[((size_t)idx * NSLOT + (blockIdx.x & (NSLOT - 1))) * SLOT_U],
        1u, __ATOMIC_RELAXED, __HIP_MEMORY_SCOPE_AGENT);
  }
}

__device__ __forceinline__ void stage_wait(int idx, unsigned cnt) {
  if (threadIdx.x < 64) {
    const unsigned* base = &g_flags[(size_t)idx * NSLOT * SLOT_U];
    int spins = 0;
    for (;;) {
      unsigned v = 0u;
      if (threadIdx.x < NSLOT)
        v = __hip_atomic_load(base + (size_t)threadIdx.x * SLOT_U,
                              __ATOMIC_RELAXED, __HIP_MEMORY_SCOPE_AGENT);
      #pragma unroll
      for (int o = 16; o > 0; o >>= 1) v += __shfl_down(v, o, 64);
      v = __shfl(v, 0, 64);
      if (v >= cnt) break;
      if (spins < 32)       __builtin_amdgcn_s_sleep(2);
      else if (spins < 256) __builtin_amdgcn_s_sleep(16);
      else                  __builtin_amdgcn_s_sleep(64);
      ++spins;
    }
  }
  __syncthreads();
  asm volatile("" ::: "memory");
}

// ---------------- LN helpers -------------------------------------------------
__device__ __forceinline__ float bred_sum(float v, float* s_red) {
  #pragma unroll
  for (int o = 32; o > 0; o >>= 1) v += __shfl_down(v, o, 64);
  __syncthreads();
  if ((threadIdx.x & 63) == 0) s_red[threadIdx.x >> 6] = v;
  __syncthreads();
  return s_red[0] + s_red[1] + s_red[2] + s_red[3];
}

__device__ void ln_inplace(float* row, const float* gam, const float* bet, float* s_red) {
  float ps = 0.f;
  for (int d = threadIdx.x; d < D; d += NT) ps += row[d];
  const float m = bred_sum(ps, s_red) * (1.0f / 640.0f);
  float pv = 0.f;
  for (int d = threadIdx.x; d < D; d += NT) { float t = row[d] - m; pv += t * t; }
  const float var = bred_sum(pv, s_red) * (1.0f / 640.0f);
  const float rstd = 1.0f / sqrtf(var + 1e-6f);
  for (int d = threadIdx.x; d < D; d += NT)
    row[d] = (row[d] - m) * rstd * gam[d] + bet[d];
  __syncthreads();
}

// =================== DECODE STAGES ===========================================

// Q: blocks [0,128): h=bid>>4, s=bid&15. depth slice [s*40,+40), cols head h q/k/v.
__device__ void st_Q(const Par& p, int l, float* s_xs) {
  const int bid = blockIdx.x, tid = threadIdx.x;
  const int h = bid >> 4, s = bid & 15;
  if (tid < 160) {
    const int b = tid / 40, dd = tid % 40;
    float v;
    if (l == 0) v = p.emb[(size_t)ldci(&g_tok[b]) * D + s * 40 + dd];
    else        v = ldc(&g_x[b * D + s * 40 + dd]);
    s_xs[b * 40 + dd] = v;
    if (l == 0 && h == 0) stc(&g_x[b * D + s * 40 + dd], v);  // publish emb row
  }
  __syncthreads();
  if (tid < 240) {
    const int m = tid / 80, j = tid % 80, col = h * 80 + j;
    const float* W = (m == 0 ? p.Wq : m == 1 ? p.Wk : p.Wv) + (size_t)l * D * D + col;
    const int d0 = s * 40;
    float a0 = 0, a1 = 0, a2 = 0, a3 = 0;
    for (int dd = 0; dd < 40; ++dd) {
      const float w = W[(size_t)(d0 + dd) * D];
      a0 += s_xs[0 * 40 + dd] * w; a1 += s_xs[1 * 40 + dd] * w;
      a2 += s_xs[2 * 40 + dd] * w; a3 += s_xs[3 * 40 + dd] * w;
    }
    float* o = g_qkvp + ((size_t)s * 1920 + m * 640 + col) * B;
    stc(o + 0, a0); stc(o + 1, a1); stc(o + 2, a2); stc(o + 3, a3);
  }
}

// AW: blocks [128,192): h=(bid-128)>>3, c=(bid-128)&7. pos = current position.
__device__ void st_AW(const Par& p, int l, int pos,
                      float* s_q, float* s_k, float* s_v, float* s_o, float* s_sc, float* s_wo) {
  const int idx = blockIdx.x - 128, h = idx >> 3, c = idx & 7, tid = threadIdx.x;
  // reduce qkv partials
  for (int task = tid; task < 960; task += NT) {
    const int m = task / 320, rem = task % 320, j = rem >> 2, b = rem & 3;
    const int col = m * 640 + h * 80 + j;
    const float* pp = g_qkvp + (size_t)col * B + b;
    float a = 0.f;
    #pragma unroll
    for (int s = 0; s < 16; ++s) a += ldc(pp + (size_t)s * 1920 * B);
    a += (m == 0 ? p.bq : m == 1 ? p.bk : p.bv)[(size_t)l * D + h * 80 + j];
    (m == 0 ? s_q : m == 1 ? s_k : s_v)[b * 80 + j] = a;
  }
  __syncthreads();
  if (c == 0) {  // publish new K/V to cache
    for (int task = tid; task < 2 * B * DH; task += NT) {
      const int which = task / 320, rem = task % 320, b = rem / 80, j = rem % 80;
      const float val = (which == 0 ? s_k : s_v)[b * 80 + j];
      float* dst = (which == 0 ? g_Kc : g_Vc) + KCIDX(l, b, h, pos, j);
      stc(dst, val);
    }
  }
  const int nk = pos + 1;
  // scores
  for (int task = tid; task < 4 * nk; task += NT) {
    const int b = task / nk, kp = task % nk;
    const float* qq = s_q + b * 80;
    float sd = 0.f;
    if (kp == pos) {
      const float* kk = s_k + b * 80;
      for (int j = 0; j < 80; ++j) sd += qq[j] * kk[j];
    } else {
      const float* kk = g_Kc + KCIDX(l, b, h, kp, 0);
      for (int j = 0; j < 80; ++j) sd += qq[j] * ldc(kk + j);
    }
    s_sc[b * 33 + kp] = sd / 8.94427190999915878564f;
  }
  __syncthreads();
  if (tid < 4) {
    const int b = tid;
    float m = -1e30f;
    for (int k = 0; k < nk; ++k) m = fmaxf(m, s_sc[b * 33 + k]);
    float sum = 0.f;
    for (int k = 0; k < nk; ++k) { float e = expf(s_sc[b * 33 + k] - m); s_sc[b * 33 + k] = e; sum += e; }
    s_sc[132 + b] = 1.0f / sum;
  }
  __syncthreads();
  // o
  for (int task = tid; task < 320; task += NT) {
    const int b = task / 80, j = task % 80;
    float acc = 0.f;
    for (int kp = 0; kp < nk; ++kp) {
      const float vv = (kp == pos) ? s_v[b * 80 + j] : ldc(&g_Vc[KCIDX(l, b, h, kp, j)]);
      acc += s_sc[b * 33 + kp] * vv;
    }
    s_o[b * 80 + j] = acc * s_sc[132 + b];
  }
  __syncthreads();
  // Wo partial: cols [c*80,+80), depth rows h*80+[0,80) split in 3 subs
  if (tid < 240) {
    const int j = tid % 80, sub = tid / 80;
    const int col = c * 80 + j;
    const int d0 = sub * 27, d1 = (sub == 2) ? 80 : d0 + 27;
    const float* Wo = p.Wo + (size_t)l * D * D + col;
    float a0 = 0, a1 = 0, a2 = 0, a3 = 0;
    for (int dd = d0; dd < d1; ++dd) {
      const float w = Wo[(size_t)(h * 80 + dd) * D];
      a0 += s_o[0 * 80 + dd] * w; a1 += s_o[1 * 80 + dd] * w;
      a2 += s_o[2 * 80 + dd] * w; a3 += s_o[3 * 80 + dd] * w;
    }
    float* t = s_wo + (j * 3 + sub) * 4;
    t[0] = a0; t[1] = a1; t[2] = a2; t[3] = a3;
  }
  __syncthreads();
  if (tid < 80) {
    const int j = tid, col = c * 80 + j;
    #pragma unroll
    for (int b = 0; b < 4; ++b) {
      const float a = s_wo[(j * 3 + 0) * 4 + b] + s_wo[(j * 3 + 1) * 4 + b] + s_wo[(j * 3 + 2) * 4 + b];
      stc(&g_opart[((size_t)h * D + col) * B + b], a);
    }
  }
}

// RF: blocks [192,196): b = bid-192. residual + LN1 -> g_h1
__device__ void st_RF(const Par& p, int l, float* s_row, float* s_red) {
  const int b = blockIdx.x - 192, tid = threadIdx.x;
  for (int col = tid; col < D; col += NT) {
    float a = ldc(&g_x[b * D + col]) + p.bo[(size_t)l * D + col];
    #pragma unroll
    for (int h = 0; h < 8; ++h) a += ldc(&g_opart[((size_t)h * D + col) * B + b]);
    s_row[col] = a;
  }
  __syncthreads();
  ln_inplace(s_row, p.ln1s + (size_t)l * D, p.ln1b + (size_t)l * D, s_red);
  for (int col = tid; col < D; col += NT) stc(&g_h1[b * D + col], s_row[col]);
}

// F1: blocks [196,356): s=idx/10 in [0,16), cg=idx%10. FFN1 partials.
__device__ void st_F1(const Par& p, int l, float* s_xs) {
  const int idx = blockIdx.x - 196, s = idx / 10, cg = idx % 10, tid = threadIdx.x;
  if (tid < 160) {
    const int b = tid / 40, dd = tid % 40;
    s_xs[b * 40 + dd] = ldc(&g_h1[b * D + s * 40 + dd]);
  }
  __syncthreads();
  const int col = cg * 256 + tid;
  const float* W = p.W1 + (size_t)l * D * FF + col;
  float a0 = 0, a1 = 0, a2 = 0, a3 = 0;
  for (int dd = 0; dd < 40; ++dd) {
    const float w = W[(size_t)(s * 40 + dd) * FF];
    a0 += s_xs[0 * 40 + dd] * w; a1 += s_xs[1 * 40 + dd] * w;
    a2 += s_xs[2 * 40 + dd] * w; a3 += s_xs[3 * 40 + dd] * w;
  }
  float* o = g_f1p + ((size_t)s * FF + col) * B;
  stc(o + 0, a0); stc(o + 1, a1); stc(o + 2, a2); stc(o + 3, a3);
}

// F2: blocks [356,484): c=idx>>2 in [0,32), g=idx&3. reduce+relu then W2 slice.
__device__ void st_F2(const Par& p, int l, float* s_f) {
  const int idx = blockIdx.x - 356, c = idx >> 2, g = idx & 3, tid = threadIdx.x;
  for (int task = tid; task < 320; task += NT) {
    const int fj = task >> 2, b = task & 3;
    const int fcol = c * 80 + fj;
    const float* pp = g_f1p + (size_t)fcol * B + b;
    float a = 0.f;
    #pragma unroll
    for (int s = 0; s < 16; ++s) a += ldc(pp + (size_t)s * FF * B);
    a += p.b1[(size_t)l * FF + fcol];
    s_f[fj * 4 + b] = fmaxf(a, 0.f);
  }
  __syncthreads();
  if (tid < 160) {
    const int col = g * 160 + tid;
    const float* W = p.W2 + (size_t)l * FF * D + col;
    float a0 = 0, a1 = 0, a2 = 0, a3 = 0;
    for (int fj = 0; fj < 80; ++fj) {
      const float w = W[(size_t)(c * 80 + fj) * D];
      a0 += s_f[fj * 4 + 0] * w; a1 += s_f[fj * 4 + 1] * w;
      a2 += s_f[fj * 4 + 2] * w; a3 += s_f[fj * 4 + 3] * w;
    }
    float* o = g_f2p + ((size_t)c * D + col) * B;
    stc(o + 0, a0); stc(o + 1, a1); stc(o + 2, a2); stc(o + 3, a3);
  }
}

// RQ / RL: blocks [484,488): b. residual + LN2(lprev) -> g_x
__device__ void st_RQ(const Par& p, int lprev, float* s_row, float* s_red) {
  const int b = blockIdx.x - 484, tid = threadIdx.x;
  for (int col = tid; col < D; col += NT) {
    float a = ldc(&g_h1[b * D + col]) + p.b2[(size_t)lprev * D + col];
    #pragma unroll 8
    for (int c = 0; c < 32; ++c) a += ldc(&g_f2p[((size_t)c * D + col) * B + b]);
    s_row[col] = a;
  }
  __syncthreads();
  ln_inplace(s_row, p.ln2s + (size_t)lprev * D, p.ln2b + (size_t)lprev * D, s_red);
  for (int col = tid; col < D; col += NT) stc(&g_x[b * D + col], s_row[col]);
}

// LM: blocks [0,938): 32 cols each, depth split 8x80.
__device__ void st_LM(const Par& p, float* s_xf, float* s_part, unsigned long long* s_key) {
  const int bid = blockIdx.x, tid = threadIdx.x;
  for (int i = tid; i < B * D; i += NT) s_xf[i] = ldc(&g_x[i]);
  __syncthreads();
  const int sg = tid >> 5, cj = tid & 31;
  const int col = bid * 32 + cj;
  float a0 = 0, a1 = 0, a2 = 0, a3 = 0;
  if (col < V) {
    const float* W = p.lmW + (size_t)sg * 80 * V + col;
    for (int dd = 0; dd < 80; ++dd) {
      const float w = W[(size_t)dd * V];
      const int d = sg * 80 + dd;
      a0 += s_xf[0 * D + d] * w; a1 += s_xf[1 * D + d] * w;
      a2 += s_xf[2 * D + d] * w; a3 += s_xf[3 * D + d] * w;
    }
  }
  float* t = s_part + (sg * 32 + cj) * 4;
  t[0] = a0; t[1] = a1; t[2] = a2; t[3] = a3;
  __syncthreads();
  if (tid < 128) {
    const int cj2 = tid >> 2, b = tid & 3, col2 = bid * 32 + cj2;
    unsigned long long key = 0ull;
    if (col2 < V) {
      float a = p.lmb[col2];
      #pragma unroll
      for (int sg2 = 0; sg2 < 8; ++sg2) a += s_part[(sg2 * 32 + cj2) * 4 + b];
      unsigned u = __float_as_uint(a);
      u = (u & 0x80000000u) ? ~u : (u | 0x80000000u);
      key = ((unsigned long long)u << 32) | (unsigned)(V - col2);
    }
    s_key[cj2 * 4 + b] = key;
  }
  __syncthreads();
  if (tid < 4) {
    unsigned long long k0 = 0ull;
    for (int cj2 = 0; cj2 < 32; ++cj2) {
      const unsigned long long k = s_key[cj2 * 4 + tid];
      if (k > k0) k0 = k;
    }
    stcu64(&g_keys[(size_t)bid * B + tid], k0);
  }
}

// CTL: block 1023
__device__ void st_CTL(int t, unsigned long long* s_k64) {
  const int tid = threadIdx.x;
  for (int b = 0; b < B; ++b) {
    unsigned long long k = 0ull;
    for (int i = tid; i < LM_NB; i += NT) {
      const unsigned long long kk = ldcu64(&g_keys[(size_t)i * B + b]);
      if (kk > k) k = kk;
    }
    #pragma unroll
    for (int o = 32; o > 0; o >>= 1) {
      const unsigned long long kk = __shfl_down(k, o, 64);
      if (kk > k) k = kk;
    }
    __syncthreads();
    if ((tid & 63) == 0) s_k64[tid >> 6] = k;
    __syncthreads();
    if (tid == 0) {
      unsigned long long k0 = s_k64[0];
      #pragma unroll
      for (int q = 1; q < 4; ++q) if (s_k64[q] > k0) k0 = s_k64[q];
      const int tok = V - (int)(unsigned)(k0 & 0xFFFFFFFFull);
      stci(&g_tok[b], tok);
      stci(&g_tokens[b * SEQ + t + 1], tok);
    }
    __syncthreads();
  }
  if (tid == 0) {
    int stop = (t == MAXLEN - 1) ? 1 : 0;
    bool ae = true;
    for (int b = 0; b < B; ++b) ae = ae && (ldci(&g_tok[b]) == EOS_TOK);
    if (ae) stop = 1;
    stci(&g_stop, stop);
  }
}

// =================== PREFILL STAGES (36 rows) ================================

// Qp: blocks [0,192): h=idx/24, s=(idx%24)/3 in [0,8), rg=idx%3. 12 rows, depth 80.
__device__ void st_Qp(const Par& p, int l, float* s_a) {
  const int idx = blockIdx.x, tid = threadIdx.x;
  const int h = idx / 24, rem = idx % 24, s = rem / 3, rg = rem % 3;
  const int r0 = rg * 12, d0 = s * 80;
  for (int i = tid; i < 960; i += NT) {
    const int ri = i / 80, dd = i % 80;
    s_a[i] = ldc(&g_xp[(r0 + ri) * D + d0 + dd]);
  }
  __syncthreads();
  if (tid < 240) {
    const int m = tid / 80, j = tid % 80, col = h * 80 + j;
    const float* W = (m == 0 ? p.Wq : m == 1 ? p.Wk : p.Wv) + (size_t)l * D * D + col;
    float acc[12];
    #pragma unroll
    for (int ri = 0; ri < 12; ++ri) acc[ri] = 0.f;
    for (int dd = 0; dd < 80; ++dd) {
      const float w = W[(size_t)(d0 + dd) * D];
      #pragma unroll
      for (int ri = 0; ri < 12; ++ri) acc[ri] += s_a[ri * 80 + dd] * w;
    }
    float* o = g_qkvpP + ((size_t)s * 1920 + m * 640 + col) * NR_P + r0;
    #pragma unroll
    for (int ri = 0; ri < 12; ++ri) stc(o + ri, acc[ri]);
  }
}

// AWp1: blocks [192,224): h=idx>>2, c=idx&3: positions {c, c+4, c+8}. reduce -> q global, K/V cache.
__device__ void st_AWp1(const Par& p, int l) {
  const int idx = blockIdx.x - 192, h = idx >> 2, c = idx & 3, tid = threadIdx.x;
  for (int pp = c; pp < NPOS_P; pp += 4) {
    for (int task = tid; task < 960; task += NT) {
      const int m = task / 320, rem = task % 320, j = rem >> 2, b = rem & 3;
      const int r = pp * 4 + b;
      const int col = m * 640 + h * 80 + j;
      const float* q = g_qkvpP + (size_t)col * NR_P + r;
      float a = 0.f;
      #pragma unroll
      for (int s = 0; s < 8; ++s) a += ldc(q + (size_t)s * 1920 * NR_P);
      a += (m == 0 ? p.bq : m == 1 ? p.bk : p.bv)[(size_t)l * D + h * 80 + j];
      if (m == 0)      stc(&g_qP[((size_t)h * NR_P + r) * DH + j], a);
      else if (m == 1) stc(&g_Kc[KCIDX(l, b, h, pp, j)], a);
      else             stc(&g_Vc[KCIDX(l, b, h, pp, j)], a);
    }
  }
}

// AWp2: blocks [224,256): h=idx>>2, rg=idx&3: rows [rg*9, rg*9+9). attn + Wo.
__device__ void st_AWp2(const Par& p, int l, float* s_a, float* s_b, float* s_c) {
  const int idx = blockIdx.x - 224, h = idx >> 2, rg = idx & 3, tid = threadIdx.x;
  const int r0 = rg * 9;
  for (int i = tid; i < 720; i += NT) {
    const int ri = i / 80, j = i % 80;
    s_a[i] = ldc(&g_qP[((size_t)h * NR_P + r0 + ri) * DH + j]);
  }
  __syncthreads();
  for (int task = tid; task < 81; task += NT) {
    const int ri = task / 9, kp = task % 9;
    const int r = r0 + ri, pos = r >> 2, b = r & 3;
    if (kp <= pos) {
      const float* kk = g_Kc + KCIDX(l, b, h, kp, 0);
      const float* qq = s_a + ri * 80;
      float sd = 0.f;
      for (int j = 0; j < 80; ++j) sd += qq[j] * ldc(kk + j);
      s_c[ri * 9 + kp] = sd / 8.94427190999915878564f;
    }
  }
  __syncthreads();
  if (tid < 9) {
    const int ri = tid, r = r0 + ri, pos = r >> 2;
    float m = -1e30f;
    for (int k = 0; k <= pos; ++k) m = fmaxf(m, s_c[ri * 9 + k]);
    float sum = 0.f;
    for (int k = 0; k <= pos; ++k) { float e = expf(s_c[ri * 9 + k] - m); s_c[ri * 9 + k] = e; sum += e; }
    s_c[81 + ri] = 1.0f / sum;
  }
  __syncthreads();
  for (int task = tid; task < 720; task += NT) {
    const int ri = task / 80, j = task % 80;
    const int r = r0 + ri, pos = r >> 2, b = r & 3;
    float acc = 0.f;
    for (int kp = 0; kp <= pos; ++kp)
      acc += s_c[ri * 9 + kp] * ldc(&g_Vc[KCIDX(l, b, h, kp, j)]);
    s_b[ri * 80 + j] = acc * s_c[81 + ri];
  }
  __syncthreads();
  if (tid < 160) {
    for (int pass = 0; pass < 4; ++pass) {
      const int col = pass * 160 + tid;
      const float* Wo = p.Wo + (size_t)l * D * D + col;
      float acc[9];
      #pragma unroll
      for (int ri = 0; ri < 9; ++ri) acc[ri] = 0.f;
      for (int dd = 0; dd < 80; ++dd) {
        const float w = Wo[(size_t)(h * 80 + dd) * D];
        #pragma unroll
        for (int ri = 0; ri < 9; ++ri) acc[ri] += s_b[ri * 80 + dd] * w;
      }
      #pragma unroll
      for (int ri = 0; ri < 9; ++ri)
        stc(&g_opartP[((size_t)h * D + col) * NR_P + r0 + ri], acc[ri]);
    }
  }
}

// RFp: blocks [0,36): r. residual + LN1 -> g_h1p
__device__ void st_RFp(const Par& p, int l, float* s_row, float* s_red) {
  const int r = blockIdx.x, tid = threadIdx.x;
  for (int col = tid; col < D; col += NT) {
    float a = ldc(&g_xp[r * D + col]) + p.bo[(size_t)l * D + col];
    #pragma unroll
    for (int h = 0; h < 8; ++h) a += ldc(&g_opartP[((size_t)h * D + col) * NR_P + r]);
    s_row[col] = a;
  }
  __syncthreads();
  ln_inplace(s_row, p.ln1s + (size_t)l * D, p.ln1b + (size_t)l * D, s_red);
  for (int col = tid; col < D; col += NT) stc(&g_h1p[r * D + col], s_row[col]);
}

// F1p: blocks [0,240): s=idx/30 in [0,8), cg=(idx%30)/3 in [0,10), rg=idx%3.
__device__ void st_F1p(const Par& p, int l, float* s_a) {
  const int idx = blockIdx.x, tid = threadIdx.x;
  const int s = idx / 30, rem = idx % 30, cg = rem / 3, rg = rem % 3;
  const int r0 = rg * 12, d0 = s * 80;
  for (int i = tid; i < 960; i += NT) {
    const int ri = i / 80, dd = i % 80;
    s_a[i] = ldc(&g_h1p[(r0 + ri) * D + d0 + dd]);
  }
  __syncthreads();
  const int col = cg * 256 + tid;
  const float* W = p.W1 + (size_t)l * D * FF + col;
  float acc[12];
  #pragma unroll
  for (int ri = 0; ri < 12; ++ri) acc[ri] = 0.f;
  for (int dd = 0; dd < 80; ++dd) {
    const float w = W[(size_t)(d0 + dd) * FF];
    #pragma unroll
    for (int ri = 0; ri < 12; ++ri) acc[ri] += s_a[ri * 80 + dd] * w;
  }
  float* o = g_f1pP + ((size_t)s * FF + col) * NR_P + r0;
  #pragma unroll
  for (int ri = 0; ri < 12; ++ri) stc(o + ri, acc[ri]);
}

// F2p: blocks [240,336): c=idx/3 in [0,32), rg=idx%3.
__device__ void st_F2p(const Par& p, int l, float* s_c) {
  const int idx = blockIdx.x - 240, c = idx / 3, rg = idx % 3, tid = threadIdx.x;
  const int r0 = rg * 12;
  for (int task = tid; task < 960; task += NT) {
    const int ri = task / 80, fj = task % 80;
    const int fcol = c * 80 + fj;
    const float* pp = g_f1pP + (size_t)fcol * NR_P + r0 + ri;
    float a = 0.f;
    #pragma unroll
    for (int s = 0; s < 8; ++s) a += ldc(pp + (size_t)s * FF * NR_P);
    a += p.b1[(size_t)l * FF + fcol];
    s_c[ri * 80 + fj] = fmaxf(a, 0.f);
  }
  __syncthreads();
  for (int pass = 0; pass < 3; ++pass) {
    const int col = pass * 256 + tid;
    if (col < D) {
      const float* W = p.W2 + (size_t)l * FF * D + col;
      float acc[12];
      #pragma unroll
      for (int ri = 0; ri < 12; ++ri) acc[ri] = 0.f;
      for (int fj = 0; fj < 80; ++fj) {
        const float w = W[(size_t)(c * 80 + fj) * D];
        #pragma unroll
        for (int ri = 0; ri < 12; ++ri) acc[ri] += s_c[ri * 80 + fj] * w;
      }
      float* o = g_f2pP + ((size_t)c * D + col) * NR_P + r0;
      #pragma unroll
      for (int ri = 0; ri < 12; ++ri) stc(o + ri, acc[ri]);
    }
  }
}

// RQp: blocks [0,36): r. residual + LN2 -> g_xp
__device__ void st_RQp(const Par& p, int l, float* s_row, float* s_red) {
  const int r = blockIdx.x, tid = threadIdx.x;
  for (int col = tid; col < D; col += NT) {
    float a = ldc(&g_h1p[r * D + col]) + p.b2[(size_t)l * D + col];
    #pragma unroll 8
    for (int c = 0; c < 32; ++c) a += ldc(&g_f2pP[((size_t)c * D + col) * NR_P + r]);
    s_row[col] = a;
  }
  __syncthreads();
  ln_inplace(s_row, p.ln2s + (size_t)l * D, p.ln2b + (size_t)l * D, s_red);
  for (int col = tid; col < D; col += NT) stc(&g_xp[r * D + col], s_row[col]);
}

// RLp: blocks [0,4): b -> rows 32+b (position 8). residual + LN2(5) -> g_x
__device__ void st_RLp(const Par& p, float* s_row, float* s_red) {
  const int b = blockIdx.x, r = 32 + b, tid = threadIdx.x;
  for (int col = tid; col < D; col += NT) {
    float a = ldc(&g_h1p[r * D + col]) + p.b2[(size_t)(NL - 1) * D + col];
    #pragma unroll 8
    for (int c = 0; c < 32; ++c) a += ldc(&g_f2pP[((size_t)c * D + col) * NR_P + r]);
    s_row[col] = a;
  }
  __syncthreads();
  ln_inplace(s_row, p.ln2s + (size_t)(NL - 1) * D, p.ln2b + (size_t)(NL - 1) * D, s_red);
  for (int col = tid; col < D; col += NT) stc(&g_x[b * D + col], s_row[col]);
}

// =================== MAIN ====================================================
__global__ __launch_bounds__(NT, 4) void tfgen(Par p) {
  __shared__ float s_x[2560];
  __shared__ float s_a[1024];
  __shared__ float s_b[768];
  __shared__ float s_c[1024];
  __shared__ float s_wo[960];
  __shared__ float s_red[4];
  __shared__ unsigned long long s_key[128];
  __shared__ int s_ctl[4];

  const int bid = blockIdx.x, tid = threadIdx.x;
  int ep = 0;

  // ---- INIT: zero flags (striped layout), prefill embeddings, token buffer
  {
    unsigned* f = g_flags + (size_t)bid * NSLOT * SLOT_U;
    for (int i = tid; i < NSLOT * SLOT_U; i += NT) f[i] = 0u;
  }
  if (bid < NR_P) {
    const int pos = bid >> 2, b = bid & 3;
    const int tk = (pos == 0) ? 1 : p.iw[b * INITLEN + pos - 1];
    for (int d = tid; d < D; d += NT) stc(&g_xp[bid * D + d], p.emb[(size_t)tk * D + d]);
  }
  if (bid == NBLK - 1) {
    for (int i = tid; i < B * SEQ; i += NT) {
      const int b = i / SEQ, pos = i % SEQ;
      int tk = 0;
      if (pos == 0) tk = 1;
      else if (pos <= INITLEN) tk = p.iw[b * INITLEN + pos - 1];
      stci(&g_tokens[i], tk);
    }
  }
  gsync_full();

  // ---- PREFILL
  int eRQ = -1, eF2last = -1;
  for (int l = 0; l < NL; ++l) {
    const int eQ = ep++;
    if (bid < 192) { if (l > 0) stage_wait(eRQ, 36); st_Qp(p, l, s_a); stage_done(eQ); }
    const int eA1 = ep++;
    if (bid >= 192 && bid < 224) { stage_wait(eQ, 192); st_AWp1(p, l); stage_done(eA1); }
    const int eA2 = ep++;
    if (bid >= 224 && bid < 256) { stage_wait(eA1, 32); st_AWp2(p, l, s_a, s_b, s_c); stage_done(eA2); }
    const int eRF = ep++;
    if (bid < NR_P) { stage_wait(eA2, 32); st_RFp(p, l, s_x, s_red); stage_done(eRF); }
    const int eF1 = ep++;
    if (bid < 240) { stage_wait(eRF, 36); st_F1p(p, l, s_a); stage_done(eF1); }
    const int eF2 = ep++;
    if (bid >= 240 && bid < 336) { stage_wait(eF1, 240); st_F2p(p, l, s_c); stage_done(eF2); }
    eF2last = eF2;
    if (l < NL - 1) {
      eRQ = ep++;
      if (bid < NR_P) { stage_wait(eF2, 96); st_RQp(p, l, s_x, s_red); stage_done(eRQ); }
    }
  }

  // ---- DECODE
  int eCTL = -1;
  for (int t = INITLEN;; ++t) {
    if (t == INITLEN) {
      const int eRL = ep++;
      if (bid < 4) { stage_wait(eF2last, 96); st_RLp(p, s_x, s_red); stage_done(eRL); }
      const int eLM = ep++;
      if (bid < LM_NB) { stage_wait(eRL, 4); st_LM(p, s_x, s_a, s_key); stage_done(eLM); }
      eCTL = ep++;
      if (bid == NBLK - 1) { stage_wait(eLM, LM_NB); st_CTL(t, (unsigned long long*)s_key); stage_done(eCTL); }
    } else {
      int eSrc = -1;  // RQ flag of current layer input
      int eF2d = -1;
      for (int l = 0; l < NL; ++l) {
        const int eQ = ep++;
        if (bid < 128) { if (l > 0) stage_wait(eSrc, 4); st_Q(p, l, s_a); stage_done(eQ); }
        const int eAW = ep++;
        if (bid >= 128 && bid < 192) {
          stage_wait(eQ, 128);
          st_AW(p, l, t, s_a, s_a + 320, s_a + 640, s_b, s_c, s_wo);
          stage_done(eAW);
        }
        const int eRF = ep++;
        if (bid >= 192 && bid < 196) { stage_wait(eAW, 64); st_RF(p, l, s_x, s_red); stage_done(eRF); }
        const int eF1 = ep++;
        if (bid >= 196 && bid < 356) { stage_wait(eRF, 4); st_F1(p, l, s_a); stage_done(eF1); }
        eF2d = ep++;
        if (bid >= 356 && bid < 484) { stage_wait(eF1, 160); st_F2(p, l, s_c); stage_done(eF2d); }
        if (l < NL - 1) {
          eSrc = ep++;
          if (bid >= 484 && bid < 488) { stage_wait(eF2d, 128); st_RQ(p, l, s_x, s_red); stage_done(eSrc); }
        }
      }
      const int eRL = ep++;
      if (bid >= 484 && bid < 488) { stage_wait(eF2d, 128); st_RQ(p, NL - 1, s_x, s_red); stage_done(eRL); }
      const int eLM = ep++;
      if (bid < LM_NB) { stage_wait(eRL, 4); st_LM(p, s_x, s_a, s_key); stage_done(eLM); }
      eCTL = ep++;
      if (bid == NBLK - 1) { stage_wait(eLM, LM_NB); st_CTL(t, (unsigned long long*)s_key); stage_done(eCTL); }
    }
    // all blocks learn the verdict
    stage_wait(eCTL, 1);
    if (tid == 0) s_ctl[0] = ldci(&g_stop);
    __syncthreads();
    if (s_ctl[0]) break;
  }

  if (bid == 0) {
    for (int i = tid; i < B * MAXLEN; i += NT) {
      const int b = i >> 5, j = i & 31;
      p.out[i] = ldci(&g_tokens[b * SEQ + j + 1]);
    }
  }
}

extern "C" void kernel_launch(void* const* d_in, const int* in_sizes, int n_in,
                              void* d_out, int out_size, void* d_ws, size_t ws_size,
                              hipStream_t stream)
{
  (void)in_sizes; (void)n_in; (void)out_size; (void)d_ws; (void)ws_size;
  Par p;
  p.iw   = (const int*)  d_in[0];
  p.emb  = (const float*)d_in[2];
  p.Wq   = (const float*)d_in[3];  p.bq   = (const float*)d_in[4];
  p.Wk   = (const float*)d_in[5];  p.bk   = (const float*)d_in[6];
  p.Wv   = (const float*)d_in[7];  p.bv   = (const float*)d_in[8];
  p.Wo   = (const float*)d_in[9];  p.bo   = (const float*)d_in[10];
  p.ln1s = (const float*)d_in[11]; p.ln1b = (const float*)d_in[12];
  p.W1   = (const float*)d_in[13]; p.b1   = (const float*)d_in[14];
  p.W2   = (const float*)d_in[15]; p.b2   = (const float*)d_in[16];
  p.ln2s = (const float*)d_in[17]; p.ln2b = (const float*)d_in[18];
  p.lmW  = (const float*)d_in[19]; p.lmb  = (const float*)d_in[20];
  p.out  = (int*)d_out;

  void* args[] = { (void*)&p };
  hipError_t err = hipLaunchCooperativeKernel((const void*)tfgen, dim3(NBLK), dim3(NT),
                                              args, 0, stream);
  if (err != hipSuccess) {
    // __launch_bounds__(256,4) guarantees 4 blocks/CU co-residency on 256 CUs.
    hipLaunchKernelGGL(tfgen, dim3(NBLK), dim3(NT), 0, stream, p);
  }
}